// Round 7
// baseline (52.666 us; speedup 1.0000x reference)
//
#include <hip/hip_runtime.h>

// FutureEncoder: out[b,t,:] = sum_j softmax_j(dot(x[b,t], x[b,t+1+j])) * x[b,t+1+j],
// j in [0,16), valid iff t+1+j < S. fp32 throughout.
//
// Round 7: block-level row sharing. A 512-thread block (8 waves) owns 32
// consecutive t's; union of query+window rows = 48 rows = 6 chunks x 8 rows,
// streamed through a double-buffered 64KB LDS with async global_load_lds
// (width=16). Each row fetched ONCE per block (1.5 rows/t vs ~9 before):
// read traffic ~49MB + 34MB write -> ~13us floor. Chunk c+1's loads are
// issued before computing chunk c (2-phase pipeline); row consumption is
// ds_read_b128 from LDS. Queries come from the same staged chunks.

namespace {
constexpr int kB   = 2;
constexpr int kS   = 4096;
constexpr int kH   = 1024;
constexpr int kK   = 16;
constexpr int kWaves = 8;               // waves per block
constexpr int kTPW   = 4;               // t's per wave
constexpr int kTPB   = kWaves * kTPW;   // 32 t's per block
constexpr int kRows  = kTPB + kK;       // 48 union rows: t0 .. t0+47
constexpr int kCH    = 8;               // rows per chunk (1 per wave)
constexpr int kChunks = kRows / kCH;    // 6
constexpr int kFR    = kH / (64 * 4);   // 4 float4 fragments per lane per row
constexpr int kBlocks = kB * kS / kTPB; // 512 t-groups? no: 8192/32 = 256
constexpr int kXCD   = 8;
}

__global__ __launch_bounds__(512, 2)
void future_encoder_kernel(const float* __restrict__ x, float* __restrict__ out) {
  __shared__ float lds[2][kCH][kH];     // 64 KB double buffer
  const int lane = (int)(threadIdx.x & 63);
  const int wid  = (int)(threadIdx.x >> 6);      // 0..7

  // XCD strip swizzle: contiguous t-strips per XCD for L2 locality.
  const int vb  = (int)(blockIdx.x % kXCD) * (kBlocks / kXCD) + (int)(blockIdx.x / kXCD);
  const int t0g = vb * kTPB;
  const int b   = t0g / kS;
  const int t0  = t0g % kS;                      // 32 | 4096: no batch crossing
  const float* __restrict__ xb = x   + (size_t)b * kS * kH;
  float* __restrict__       ob = out + (size_t)b * kS * kH;
  const int col = lane * 4;
  const int tw  = kTPW * wid;                    // wave's first t (block-relative)

  // Per-wave state
  float4 xt[kTPW][kFR];                          // query fragments (filled from LDS)
  float  m[kTPW], s[kTPW];
  float4 acc[kTPW][kFR];
#pragma unroll
  for (int tt = 0; tt < kTPW; ++tt) {
    m[tt] = -1e30f;
    s[tt] = 0.f;
#pragma unroll
    for (int p = 0; p < kFR; ++p) acc[tt][p] = make_float4(0.f, 0.f, 0.f, 0.f);
  }

  // ---- prologue: stage chunk 0 (rows t0+0..t0+7; always < kS) ----
  {
    const int gr = t0 + wid;
    const float* g = xb + (size_t)gr * kH + col;
    float* l = &lds[0][wid][0];
#pragma unroll
    for (int seg = 0; seg < 4; ++seg)
      __builtin_amdgcn_global_load_lds(
          (const __attribute__((address_space(1))) void*)(g + seg * 256),
          (__attribute__((address_space(3))) void*)(l + seg * 256), 16, 0, 0);
  }
  __syncthreads();   // chunk 0 resident

#pragma unroll
  for (int c = 0; c < kChunks; ++c) {
    // ---- phase 1: issue async stage of chunk c+1 into the other buffer ----
    if (c + 1 < kChunks) {
      const int ri = (c + 1) * kCH + wid;
      int gr = t0 + ri; if (gr > kS - 1) gr = kS - 1;   // clamp; masked later
      const float* g = xb + (size_t)gr * kH + col;
      float* l = &lds[(c + 1) & 1][wid][0];
#pragma unroll
      for (int seg = 0; seg < 4; ++seg)
        __builtin_amdgcn_global_load_lds(
            (const __attribute__((address_space(1))) void*)(g + seg * 256),
            (__attribute__((address_space(3))) void*)(l + seg * 256), 16, 0, 0);
    }

    // ---- grab this wave's queries when their chunk arrives ----
    if ((wid >> 1) == c) {
#pragma unroll
      for (int tt = 0; tt < kTPW; ++tt)
#pragma unroll
        for (int p = 0; p < kFR; ++p)
          xt[tt][p] = *(const float4*)&lds[c & 1][4 * (wid & 1) + tt][p * 256 + col];
    }

    // ---- phase 2: consume chunk c from LDS ----
#pragma unroll
    for (int jr = 0; jr < kCH; ++jr) {
      const int ri  = c * kCH + jr;        // union-row index (compile-time)
      const int rel = ri - tw;             // runtime, wave-uniform
      if (rel >= 1 && rel <= kTPW - 1 + kK && (t0 + ri) < kS) {
        float4 w[kFR];
#pragma unroll
        for (int p = 0; p < kFR; ++p)
          w[p] = *(const float4*)&lds[c & 1][jr][p * 256 + col];

        // Branchless dots for all 4 t's (masked at update)
        float sc[kTPW];
#pragma unroll
        for (int tt = 0; tt < kTPW; ++tt) {
          float a0 = 0.f, a1 = 0.f;
#pragma unroll
          for (int p = 0; p < kFR; ++p) {
            a0 = fmaf(xt[tt][p].x, w[p].x, a0);
            a1 = fmaf(xt[tt][p].y, w[p].y, a1);
            a0 = fmaf(xt[tt][p].z, w[p].z, a0);
            a1 = fmaf(xt[tt][p].w, w[p].w, a1);
          }
          sc[tt] = a0 + a1;
        }

        // Batched butterfly reduce (4 chains pipeline per level)
#pragma unroll
        for (int off = 32; off >= 1; off >>= 1) {
          float other[kTPW];
#pragma unroll
          for (int tt = 0; tt < kTPW; ++tt) other[tt] = __shfl_xor(sc[tt], off, 64);
#pragma unroll
          for (int tt = 0; tt < kTPW; ++tt) sc[tt] += other[tt];
        }

        // Online-softmax updates (wave-uniform masks and scores)
#pragma unroll
        for (int tt = 0; tt < kTPW; ++tt) {
          const int d = rel - tt;
          if (d >= 1 && d <= kK) {
            const float v = sc[tt];
            if (v <= m[tt]) {
              const float p2 = __expf(v - m[tt]);
              s[tt] += p2;
#pragma unroll
              for (int p = 0; p < kFR; ++p) {
                acc[tt][p].x = fmaf(p2, w[p].x, acc[tt][p].x);
                acc[tt][p].y = fmaf(p2, w[p].y, acc[tt][p].y);
                acc[tt][p].z = fmaf(p2, w[p].z, acc[tt][p].z);
                acc[tt][p].w = fmaf(p2, w[p].w, acc[tt][p].w);
              }
            } else {
              const float r2 = __expf(m[tt] - v);   // 0 on first valid row
              m[tt] = v;
              s[tt] = fmaf(s[tt], r2, 1.f);
#pragma unroll
              for (int p = 0; p < kFR; ++p) {
                acc[tt][p].x = fmaf(acc[tt][p].x, r2, w[p].x);
                acc[tt][p].y = fmaf(acc[tt][p].y, r2, w[p].y);
                acc[tt][p].z = fmaf(acc[tt][p].z, r2, w[p].z);
                acc[tt][p].w = fmaf(acc[tt][p].w, r2, w[p].w);
              }
            }
          }
        }
      }
    }

    __syncthreads();   // buf[c&1] free for reuse; chunk c+1 loads drained
  }

  // ---- epilogue: out = acc / s  (s==0 only for t==S-1 -> exact zeros) ----
#pragma unroll
  for (int tt = 0; tt < kTPW; ++tt) {
    const float inv = (s[tt] > 0.f) ? (1.f / s[tt]) : 0.f;
    const int t = t0 + tw + tt;
#pragma unroll
    for (int p = 0; p < kFR; ++p) {
      float4 o;
      o.x = acc[tt][p].x * inv;
      o.y = acc[tt][p].y * inv;
      o.z = acc[tt][p].z * inv;
      o.w = acc[tt][p].w * inv;
      *(float4*)(ob + (size_t)t * kH + p * 256 + col) = o;
    }
  }
}

extern "C" void kernel_launch(void* const* d_in, const int* in_sizes, int n_in,
                              void* d_out, int out_size, void* d_ws, size_t ws_size,
                              hipStream_t stream) {
  const float* x = (const float*)d_in[0];
  float* out = (float*)d_out;
  hipLaunchKernelGGL(future_encoder_kernel, dim3(kBlocks), dim3(512), 0, stream,
                     x, out);
}

// Round 8
// 34.181 us; speedup vs baseline: 1.5408x; 1.5408x over previous
//
#include <hip/hip_runtime.h>

// FutureEncoder: out[b,t,:] = sum_j softmax_j(dot(x[b,t], x[b,t+1+j])) * x[b,t+1+j],
// j in [0,16), valid iff t+1+j < S. fp32 throughout.
//
// Round 8: R7 proved the traffic win (FETCH 17MB) but ran at 1 block/CU with
// 6 full-drain barriers -> 52us, occupancy 19%, VALUBusy 19%. This round keeps
// the LDS row-sharing but halves the block tile: TPB=16 t's, 32 union rows,
// 4 chunks x 8 rows, 64KB LDS double-buffer -> 2 blocks/CU, 4 waves/SIMD,
// 4 barriers, and a co-resident block to execute through each barrier drain.

namespace {
constexpr int kB     = 2;
constexpr int kS     = 4096;
constexpr int kH     = 1024;
constexpr int kK     = 16;
constexpr int kWaves = 8;                 // waves per block (512 threads)
constexpr int kTPW   = 2;                 // t's per wave
constexpr int kTPB   = kWaves * kTPW;     // 16 t's per block
constexpr int kRows  = kTPB + kK;         // 32 union rows
constexpr int kCH    = 8;                 // rows per chunk (1 per wave)
constexpr int kChunks = kRows / kCH;      // 4
constexpr int kFR    = kH / (64 * 4);     // 4 float4 fragments per lane per row
constexpr int kBlocks = kB * kS / kTPB;   // 512 -> 2 blocks/CU
constexpr int kXCD   = 8;
}

__global__ __launch_bounds__(512, 4)
void future_encoder_kernel(const float* __restrict__ x, float* __restrict__ out) {
  __shared__ float lds[2][kCH][kH];       // 64 KB double buffer
  const int lane = (int)(threadIdx.x & 63);
  const int wid  = (int)(threadIdx.x >> 6);        // 0..7

  // XCD strip swizzle: contiguous t-strips per XCD for L2 locality (512%8==0).
  const int vb  = (int)(blockIdx.x % kXCD) * (kBlocks / kXCD) + (int)(blockIdx.x / kXCD);
  const int t0g = vb * kTPB;
  const int b   = t0g / kS;
  const int t0  = t0g % kS;                        // 16 | 4096: no batch crossing
  const float* __restrict__ xb = x   + (size_t)b * kS * kH;
  float* __restrict__       ob = out + (size_t)b * kS * kH;
  const int col = lane * 4;
  const int tw  = kTPW * wid;                      // wave's first t (block-relative)

  // Per-wave state
  float4 xt[kTPW][kFR];
  float  m[kTPW], s[kTPW];
  float4 acc[kTPW][kFR];
#pragma unroll
  for (int tt = 0; tt < kTPW; ++tt) {
    m[tt] = -1e30f;
    s[tt] = 0.f;
#pragma unroll
    for (int p = 0; p < kFR; ++p) {
      acc[tt][p] = make_float4(0.f, 0.f, 0.f, 0.f);
      xt[tt][p]  = make_float4(0.f, 0.f, 0.f, 0.f);
    }
  }

  // ---- prologue: stage chunk 0 (rows t0+0..t0+7; always < kS) ----
  {
    const float* g = xb + (size_t)(t0 + wid) * kH + col;
    float* l = &lds[0][wid][0];
#pragma unroll
    for (int seg = 0; seg < 4; ++seg)
      __builtin_amdgcn_global_load_lds(
          (const __attribute__((address_space(1))) void*)(g + seg * 256),
          (__attribute__((address_space(3))) void*)(l + seg * 256), 16, 0, 0);
  }
  __syncthreads();   // chunk 0 resident

#pragma unroll
  for (int c = 0; c < kChunks; ++c) {
    // ---- issue async stage of chunk c+1 into the other buffer ----
    if (c + 1 < kChunks) {
      const int ri = (c + 1) * kCH + wid;
      int gr = t0 + ri; if (gr > kS - 1) gr = kS - 1;   // clamp; masked later
      const float* g = xb + (size_t)gr * kH + col;
      float* l = &lds[(c + 1) & 1][wid][0];
#pragma unroll
      for (int seg = 0; seg < 4; ++seg)
        __builtin_amdgcn_global_load_lds(
            (const __attribute__((address_space(1))) void*)(g + seg * 256),
            (__attribute__((address_space(3))) void*)(l + seg * 256), 16, 0, 0);
    }

    // ---- grab this wave's queries when their chunk is resident ----
    if ((wid >> 2) == c) {
      const int jq = 2 * (wid & 3);                 // local row of first query
#pragma unroll
      for (int tt = 0; tt < kTPW; ++tt)
#pragma unroll
        for (int p = 0; p < kFR; ++p)
          xt[tt][p] = *(const float4*)&lds[c & 1][jq + tt][p * 256 + col];
    }

    // ---- consume chunk c from LDS ----
#pragma unroll
    for (int jr = 0; jr < kCH; ++jr) {
      const int ri  = c * kCH + jr;        // union-row index (compile-time)
      const int rel = ri - tw;             // wave-uniform
      if (rel >= 1 && rel <= kTPW - 1 + kK && (t0 + ri) < kS) {
        float4 w[kFR];
#pragma unroll
        for (int p = 0; p < kFR; ++p)
          w[p] = *(const float4*)&lds[c & 1][jr][p * 256 + col];

        // Branchless dots for both t's (masked at update)
        float sc[kTPW];
#pragma unroll
        for (int tt = 0; tt < kTPW; ++tt) {
          float a0 = 0.f, a1 = 0.f;
#pragma unroll
          for (int p = 0; p < kFR; ++p) {
            a0 = fmaf(xt[tt][p].x, w[p].x, a0);
            a1 = fmaf(xt[tt][p].y, w[p].y, a1);
            a0 = fmaf(xt[tt][p].z, w[p].z, a0);
            a1 = fmaf(xt[tt][p].w, w[p].w, a1);
          }
          sc[tt] = a0 + a1;
        }

        // Batched butterfly reduce (2 chains pipeline per level)
#pragma unroll
        for (int off = 32; off >= 1; off >>= 1) {
          float other[kTPW];
#pragma unroll
          for (int tt = 0; tt < kTPW; ++tt) other[tt] = __shfl_xor(sc[tt], off, 64);
#pragma unroll
          for (int tt = 0; tt < kTPW; ++tt) sc[tt] += other[tt];
        }

        // Online-softmax updates (wave-uniform masks and scores)
#pragma unroll
        for (int tt = 0; tt < kTPW; ++tt) {
          const int d = rel - tt;
          if (d >= 1 && d <= kK) {
            const float v = sc[tt];
            if (v <= m[tt]) {
              const float p2 = __expf(v - m[tt]);
              s[tt] += p2;
#pragma unroll
              for (int p = 0; p < kFR; ++p) {
                acc[tt][p].x = fmaf(p2, w[p].x, acc[tt][p].x);
                acc[tt][p].y = fmaf(p2, w[p].y, acc[tt][p].y);
                acc[tt][p].z = fmaf(p2, w[p].z, acc[tt][p].z);
                acc[tt][p].w = fmaf(p2, w[p].w, acc[tt][p].w);
              }
            } else {
              const float r2 = __expf(m[tt] - v);   // 0 on first valid row
              m[tt] = v;
              s[tt] = fmaf(s[tt], r2, 1.f);
#pragma unroll
              for (int p = 0; p < kFR; ++p) {
                acc[tt][p].x = fmaf(acc[tt][p].x, r2, w[p].x);
                acc[tt][p].y = fmaf(acc[tt][p].y, r2, w[p].y);
                acc[tt][p].z = fmaf(acc[tt][p].z, r2, w[p].z);
                acc[tt][p].w = fmaf(acc[tt][p].w, r2, w[p].w);
              }
            }
          }
        }
      }
    }

    if (c + 1 < kChunks) __syncthreads();   // chunk c+1 resident; buffer safe
  }

  // ---- epilogue: out = acc / s  (s==0 only for t==S-1 -> exact zeros) ----
#pragma unroll
  for (int tt = 0; tt < kTPW; ++tt) {
    const float inv = (s[tt] > 0.f) ? (1.f / s[tt]) : 0.f;
    const int t = t0 + tw + tt;
#pragma unroll
    for (int p = 0; p < kFR; ++p) {
      float4 o;
      o.x = acc[tt][p].x * inv;
      o.y = acc[tt][p].y * inv;
      o.z = acc[tt][p].z * inv;
      o.w = acc[tt][p].w * inv;
      *(float4*)(ob + (size_t)t * kH + p * 256 + col) = o;
    }
  }
}

extern "C" void kernel_launch(void* const* d_in, const int* in_sizes, int n_in,
                              void* d_out, int out_size, void* d_ws, size_t ws_size,
                              hipStream_t stream) {
  const float* x = (const float*)d_in[0];
  float* out = (float*)d_out;
  hipLaunchKernelGGL(future_encoder_kernel, dim3(kBlocks), dim3(512), 0, stream,
                     x, out);
}